// Round 1
// baseline (1461.515 us; speedup 1.0000x reference)
//
#include <hip/hip_runtime.h>
#include <math.h>

// Problem constants: B=8, C=64, H=W=256, fp32 throughout.
constexpr int CH  = 64;      // channels
constexpr int WW  = 256;     // H == W
constexpr int HWS = WW * WW; // 65536 elements per (b,c) slab
constexpr int NB  = 8;       // batch

// ---------------------------------------------------------------------------
// Kernel 1: fused QKV 1x1-conv projection.
// One thread per pixel; x[b,:,p] (64 channels) held in registers; weight
// reads are loop-uniform -> scalar loads; 3*64*64 FMAs per thread.
// ---------------------------------------------------------------------------
__global__ __launch_bounds__(256) void qkv_kernel(
    const float* __restrict__ x,
    const float* __restrict__ Wq, const float* __restrict__ bq,
    const float* __restrict__ Wk, const float* __restrict__ bk,
    const float* __restrict__ Wv, const float* __restrict__ bv,
    float* __restrict__ Q, float* __restrict__ K, float* __restrict__ V)
{
    const int P = blockIdx.x * 256 + threadIdx.x;   // global pixel id in [0, B*HWS)
    const int b = P >> 16;                          // / 65536
    const int p = P & 65535;
    const size_t base = ((size_t)(b * CH)) << 16;   // b*C*HWS

    float xv[CH];
#pragma unroll
    for (int c = 0; c < CH; ++c)
        xv[c] = x[base + (((size_t)c) << 16) + p];

    for (int o = 0; o < CH; ++o) {
        float aq = bq[o], ak = bk[o], av = bv[o];
#pragma unroll
        for (int c = 0; c < CH; ++c) {
            const float xc = xv[c];
            aq = fmaf(Wq[o * CH + c], xc, aq);
            ak = fmaf(Wk[o * CH + c], xc, ak);
            av = fmaf(Wv[o * CH + c], xc, av);
        }
        const size_t oidx = base + (((size_t)o) << 16) + p;
        Q[oidx] = aq; K[oidx] = ak; V[oidx] = av;
    }
}

// ---------------------------------------------------------------------------
// Kernel 2: attn[b,c,i,j] = sum_h q[b,c,h,i] * k[b,c,h,j]   (q^T @ k, 256^3)
// Both operands are k-major in memory ([h][i]) -> staging is direct coalesced
// float4 copies, no transpose. 128x128 tile, 256 threads, 8x8 microtile, K-tile 8.
// Writes raw logits into d_out (attn scratch == output buffer shape).
// ---------------------------------------------------------------------------
__global__ __launch_bounds__(256) void attn_kernel(
    const float* __restrict__ Q, const float* __restrict__ Kt,
    float* __restrict__ attn)
{
    const int gid = blockIdx.x;            // bc*4 + tile
    const int bc  = gid >> 2;
    const int i0  = ((gid >> 1) & 1) * 128;
    const int j0  = (gid & 1) * 128;
    const float* q = Q  + (size_t)bc * HWS;
    const float* k = Kt + (size_t)bc * HWS;
    float* out     = attn + (size_t)bc * HWS;

    __shared__ float As[8][128];
    __shared__ float Bs[8][128];

    const int tid = threadIdx.x;
    const int tx  = tid & 15;              // 16 j-groups
    const int ty  = tid >> 4;              // 16 i-groups

    float acc[8][8];
#pragma unroll
    for (int u = 0; u < 8; ++u)
#pragma unroll
        for (int w = 0; w < 8; ++w) acc[u][w] = 0.f;

    const int sflat = tid * 4;             // 1024 floats per tile stage
    const int skk   = sflat >> 7;          // /128
    const int sii   = sflat & 127;

    for (int k0 = 0; k0 < WW; k0 += 8) {
        *(float4*)&As[skk][sii] = *(const float4*)&q[(k0 + skk) * WW + i0 + sii];
        *(float4*)&Bs[skk][sii] = *(const float4*)&k[(k0 + skk) * WW + j0 + sii];
        __syncthreads();
#pragma unroll
        for (int kk = 0; kk < 8; ++kk) {
            float a[8], bvv[8];
#pragma unroll
            for (int u = 0; u < 8; ++u) a[u]   = As[kk][ty * 8 + u];
#pragma unroll
            for (int u = 0; u < 8; ++u) bvv[u] = Bs[kk][tx * 8 + u];
#pragma unroll
            for (int u = 0; u < 8; ++u)
#pragma unroll
                for (int w = 0; w < 8; ++w)
                    acc[u][w] = fmaf(a[u], bvv[w], acc[u][w]);
        }
        __syncthreads();
    }
#pragma unroll
    for (int u = 0; u < 8; ++u) {
        float* row = out + (size_t)(i0 + ty * 8 + u) * WW + j0 + tx * 8;
#pragma unroll
        for (int w = 0; w < 8; ++w) row[w] = acc[u][w];
    }
}

// ---------------------------------------------------------------------------
// Kernel 3: softmax over the CHANNEL axis, in place on d_out.
// One thread per (b,i,j); the 64 channel values (stride HWS) live in registers.
// Max-subtracted exp: logits reach ~+/-100 so subtraction is mandatory.
// ---------------------------------------------------------------------------
__global__ __launch_bounds__(256) void softmax_kernel(float* __restrict__ attn)
{
    const int gid = blockIdx.x;            // b*256 + i
    const int b   = gid >> 8;
    const int i   = gid & 255;
    const int j   = threadIdx.x;
    float* base = attn + (((size_t)(b * CH)) << 16) + (size_t)i * WW + j;

    float vals[CH];
#pragma unroll
    for (int c = 0; c < CH; ++c) vals[c] = base[((size_t)c) << 16];

    float m = vals[0];
#pragma unroll
    for (int c = 1; c < CH; ++c) m = fmaxf(m, vals[c]);

    float s = 0.f;
#pragma unroll
    for (int c = 0; c < CH; ++c) { vals[c] = __expf(vals[c] - m); s += vals[c]; }

    const float inv = 1.0f / s;
#pragma unroll
    for (int c = 0; c < CH; ++c) base[((size_t)c) << 16] = vals[c] * inv;
}

// ---------------------------------------------------------------------------
// Kernel 4: out[b,c,i,j] = sum_m attn[b,c,i,m] * v[b,c,m,j]   IN PLACE on d_out.
// In-place safety: each block owns rows [i0, i0+64) x ALL j. Its only global
// reads of attn are those same rows, consumed into LDS before a barrier; the
// epilogue (after the final barrier) overwrites exactly those rows. No other
// block touches them.
// ---------------------------------------------------------------------------
__global__ __launch_bounds__(256) void pv_kernel(
    float* __restrict__ attn, const float* __restrict__ V)
{
    const int gid = blockIdx.x;            // bc*4 + i-tile
    const int bc  = gid >> 2;
    const int i0  = (gid & 3) * 64;
    float* p       = attn + (size_t)bc * HWS;
    const float* v = V    + (size_t)bc * HWS;

    __shared__ float As[8][64];            // attn tile, [k][i]
    __shared__ float Bs[8][256];           // v tile,    [k][j]

    const int tid = threadIdx.x;
    const int tx  = tid & 31;              // 32 j-groups (covers all 256 cols)
    const int ty  = tid >> 5;              // 8 i-groups

    float acc[8][8];
#pragma unroll
    for (int u = 0; u < 8; ++u)
#pragma unroll
        for (int w = 0; w < 8; ++w) acc[u][w] = 0.f;

    for (int m0 = 0; m0 < WW; m0 += 8) {
        if (tid < 128) {                   // stage As: 64 rows x 8 k-vals
            const int i    = tid >> 1;
            const int half = (tid & 1) * 4;
            const float4 t4 = *(const float4*)&p[(size_t)(i0 + i) * WW + m0 + half];
            As[half + 0][i] = t4.x; As[half + 1][i] = t4.y;
            As[half + 2][i] = t4.z; As[half + 3][i] = t4.w;
        }
        {                                  // stage Bs: 8 rows x 256 cols
            const int kk = tid >> 5;
            const int j  = (tid & 31) * 8;
            *(float4*)&Bs[kk][j]     = *(const float4*)&v[(size_t)(m0 + kk) * WW + j];
            *(float4*)&Bs[kk][j + 4] = *(const float4*)&v[(size_t)(m0 + kk) * WW + j + 4];
        }
        __syncthreads();
#pragma unroll
        for (int kk = 0; kk < 8; ++kk) {
            float a[8], bvv[8];
#pragma unroll
            for (int u = 0; u < 8; ++u) a[u]   = As[kk][ty * 8 + u];
#pragma unroll
            for (int u = 0; u < 8; ++u) bvv[u] = Bs[kk][tx * 8 + u];
#pragma unroll
            for (int u = 0; u < 8; ++u)
#pragma unroll
                for (int w = 0; w < 8; ++w)
                    acc[u][w] = fmaf(a[u], bvv[w], acc[u][w]);
        }
        __syncthreads();                   // final barrier also fences the in-place epilogue
    }

#pragma unroll
    for (int u = 0; u < 8; ++u) {
        float* row = p + (size_t)(i0 + ty * 8 + u) * WW + tx * 8;
#pragma unroll
        for (int w = 0; w < 8; ++w) row[w] = acc[u][w];
    }
}

// ---------------------------------------------------------------------------
extern "C" void kernel_launch(void* const* d_in, const int* in_sizes, int n_in,
                              void* d_out, int out_size, void* d_ws, size_t ws_size,
                              hipStream_t stream) {
    const float* x  = (const float*)d_in[0];
    const float* Wq = (const float*)d_in[1];
    const float* bq = (const float*)d_in[2];
    const float* Wk = (const float*)d_in[3];
    const float* bk = (const float*)d_in[4];
    const float* Wv = (const float*)d_in[5];
    const float* bv = (const float*)d_in[6];
    float* out = (float*)d_out;

    // Workspace: Q, K, V fp32, 128 MiB each (402.7 MB total).
    const size_t NELEM = (size_t)NB * CH * HWS;     // 33,554,432
    float* Q  = (float*)d_ws;
    float* Kb = Q + NELEM;
    float* Vb = Kb + NELEM;

    const int pixBlocks = (NB * HWS) / 256;         // 2048
    qkv_kernel<<<pixBlocks, 256, 0, stream>>>(x, Wq, bq, Wk, bk, Wv, bv, Q, Kb, Vb);

    const int attnBlocks = NB * CH * 4;             // 2048 (2x2 tiles of 128)
    attn_kernel<<<attnBlocks, 256, 0, stream>>>(Q, Kb, out);

    const int smBlocks = NB * WW;                   // 2048
    softmax_kernel<<<smBlocks, 256, 0, stream>>>(out);

    const int pvBlocks = NB * CH * 4;               // 2048 (i-tiles of 64)
    pv_kernel<<<pvBlocks, 256, 0, stream>>>(out, Vb);
}

// Round 2
// 895.586 us; speedup vs baseline: 1.6319x; 1.6319x over previous
//
#include <hip/hip_runtime.h>
#include <math.h>

// Problem constants: B=8, C=64, H=W=256, fp32 throughout.
constexpr int CH  = 64;      // channels
constexpr int WW  = 256;     // H == W
constexpr int HWS = WW * WW; // 65536 elements per (b,c) slab
constexpr int NB  = 8;       // batch

// ---------------------------------------------------------------------------
// Kernel 1 (v2): fused QKV projection as a tiled GEMM.
//   C[192 x 524288] = W[192 x 64] * X[64 x 524288]   (rows 0-63=Q, 64-127=K, 128-191=V)
// Block: 128-pixel N-tile, full M=192, full K=64.
// LDS: W transposed [c][m] (48 KB) + bias (768 B) + X chunk [8][128] (4 KB)
//      = 54 KB -> 3 blocks/CU.
// Thread: 24 M x 4 N (float4) register microtile = 96 accumulators.
// ---------------------------------------------------------------------------
__global__ __launch_bounds__(256) void qkv_kernel2(
    const float* __restrict__ x,
    const float* __restrict__ Wq, const float* __restrict__ bq,
    const float* __restrict__ Wk, const float* __restrict__ bk,
    const float* __restrict__ Wv, const float* __restrict__ bv,
    float* __restrict__ Q, float* __restrict__ K, float* __restrict__ V)
{
    __shared__ float Wt[64][192];   // [c][m], m = mat*64 + o
    __shared__ float Bs[192];
    __shared__ float Xs[8][128];    // K-chunk x N-tile

    const int tid = threadIdx.x;
    const int n0  = blockIdx.x * 128;   // global pixel
    const int b   = n0 >> 16;
    const int pb  = n0 & 65535;

    // Stage weights transposed into LDS (one-time; bank conflicts acceptable).
    {
        const float* Wsrc[3] = {Wq, Wk, Wv};
#pragma unroll
        for (int mat = 0; mat < 3; ++mat) {
#pragma unroll
            for (int r = 0; r < 4; ++r) {
                const int flat = r * 256 + tid;   // 0..1023
                const int o    = flat >> 4;       // 0..63
                const int c4   = (flat & 15) * 4;
                const float4 w = *(const float4*)&Wsrc[mat][o * 64 + c4];
                Wt[c4 + 0][mat * 64 + o] = w.x;
                Wt[c4 + 1][mat * 64 + o] = w.y;
                Wt[c4 + 2][mat * 64 + o] = w.z;
                Wt[c4 + 3][mat * 64 + o] = w.w;
            }
        }
        if (tid < 192)
            Bs[tid] = (tid < 64) ? bq[tid] : ((tid < 128) ? bk[tid - 64] : bv[tid - 128]);
    }

    const int mg  = tid >> 5;        // 0..7  (M-group: rows mg*24 .. mg*24+23)
    const int ng  = tid & 31;        // 0..31 (N-group: pixels ng*4 .. ng*4+3)
    const int m0  = mg * 24;
    const int pix = ng * 4;

    float4 acc[24];
#pragma unroll
    for (int m = 0; m < 24; ++m) acc[m] = make_float4(0.f, 0.f, 0.f, 0.f);

    const int skk = tid >> 5;        // staging: row 0..7
    const int sp4 = (tid & 31) * 4;  // staging: col group

    for (int c0 = 0; c0 < CH; c0 += 8) {
        __syncthreads();   // readers done with Xs (and Wt ready on iter 0)
        *(float4*)&Xs[skk][sp4] =
            *(const float4*)&x[((size_t)(b * CH + c0 + skk) << 16) + pb + sp4];
        __syncthreads();

#pragma unroll
        for (int kk = 0; kk < 8; ++kk) {
            float wv[24];
#pragma unroll
            for (int q4 = 0; q4 < 6; ++q4)
                *(float4*)&wv[q4 * 4] = *(const float4*)&Wt[c0 + kk][m0 + q4 * 4];
            const float4 xv = *(const float4*)&Xs[kk][pix];
#pragma unroll
            for (int m = 0; m < 24; ++m) {
                acc[m].x = fmaf(wv[m], xv.x, acc[m].x);
                acc[m].y = fmaf(wv[m], xv.y, acc[m].y);
                acc[m].z = fmaf(wv[m], xv.z, acc[m].z);
                acc[m].w = fmaf(wv[m], xv.w, acc[m].w);
            }
        }
    }

    float* outs[3] = {Q, K, V};
#pragma unroll
    for (int m = 0; m < 24; ++m) {
        const int gm  = m0 + m;
        const int mat = gm >> 6;
        const int ch  = gm & 63;
        const float bias = Bs[gm];
        float4 r = acc[m];
        r.x += bias; r.y += bias; r.z += bias; r.w += bias;
        *(float4*)&outs[mat][((size_t)(b * CH + ch) << 16) + pb + pix] = r;
    }
}

// ---------------------------------------------------------------------------
// Kernel 2: attn[b,c,i,j] = sum_h q[b,c,h,i] * k[b,c,h,j]   (q^T @ k, 256^3)
// ---------------------------------------------------------------------------
__global__ __launch_bounds__(256) void attn_kernel(
    const float* __restrict__ Q, const float* __restrict__ Kt,
    float* __restrict__ attn)
{
    const int gid = blockIdx.x;            // bc*4 + tile
    const int bc  = gid >> 2;
    const int i0  = ((gid >> 1) & 1) * 128;
    const int j0  = (gid & 1) * 128;
    const float* q = Q  + (size_t)bc * HWS;
    const float* k = Kt + (size_t)bc * HWS;
    float* out     = attn + (size_t)bc * HWS;

    __shared__ float As[8][128];
    __shared__ float Bs[8][128];

    const int tid = threadIdx.x;
    const int tx  = tid & 15;              // 16 j-groups
    const int ty  = tid >> 4;              // 16 i-groups

    float acc[8][8];
#pragma unroll
    for (int u = 0; u < 8; ++u)
#pragma unroll
        for (int w = 0; w < 8; ++w) acc[u][w] = 0.f;

    const int sflat = tid * 4;             // 1024 floats per tile stage
    const int skk   = sflat >> 7;          // /128
    const int sii   = sflat & 127;

    for (int k0 = 0; k0 < WW; k0 += 8) {
        *(float4*)&As[skk][sii] = *(const float4*)&q[(k0 + skk) * WW + i0 + sii];
        *(float4*)&Bs[skk][sii] = *(const float4*)&k[(k0 + skk) * WW + j0 + sii];
        __syncthreads();
#pragma unroll
        for (int kk = 0; kk < 8; ++kk) {
            float a[8], bvv[8];
#pragma unroll
            for (int u = 0; u < 8; ++u) a[u]   = As[kk][ty * 8 + u];
#pragma unroll
            for (int u = 0; u < 8; ++u) bvv[u] = Bs[kk][tx * 8 + u];
#pragma unroll
            for (int u = 0; u < 8; ++u)
#pragma unroll
                for (int w = 0; w < 8; ++w)
                    acc[u][w] = fmaf(a[u], bvv[w], acc[u][w]);
        }
        __syncthreads();
    }
#pragma unroll
    for (int u = 0; u < 8; ++u) {
        float* row = out + (size_t)(i0 + ty * 8 + u) * WW + j0 + tx * 8;
#pragma unroll
        for (int w = 0; w < 8; ++w) row[w] = acc[u][w];
    }
}

// ---------------------------------------------------------------------------
// Kernel 3: softmax over the CHANNEL axis, in place on d_out.
// ---------------------------------------------------------------------------
__global__ __launch_bounds__(256) void softmax_kernel(float* __restrict__ attn)
{
    const int gid = blockIdx.x;            // b*256 + i
    const int b   = gid >> 8;
    const int i   = gid & 255;
    const int j   = threadIdx.x;
    float* base = attn + (((size_t)(b * CH)) << 16) + (size_t)i * WW + j;

    float vals[CH];
#pragma unroll
    for (int c = 0; c < CH; ++c) vals[c] = base[((size_t)c) << 16];

    float m = vals[0];
#pragma unroll
    for (int c = 1; c < CH; ++c) m = fmaxf(m, vals[c]);

    float s = 0.f;
#pragma unroll
    for (int c = 0; c < CH; ++c) { vals[c] = __expf(vals[c] - m); s += vals[c]; }

    const float inv = 1.0f / s;
#pragma unroll
    for (int c = 0; c < CH; ++c) base[((size_t)c) << 16] = vals[c] * inv;
}

// ---------------------------------------------------------------------------
// Kernel 4: out[b,c,i,j] = sum_m attn[b,c,i,m] * v[b,c,m,j]   IN PLACE on d_out.
// Each block owns rows [i0,i0+64) x ALL j; reads them fully into LDS before
// the barrier that precedes its overwriting epilogue.
// ---------------------------------------------------------------------------
__global__ __launch_bounds__(256) void pv_kernel(
    float* __restrict__ attn, const float* __restrict__ V)
{
    const int gid = blockIdx.x;            // bc*4 + i-tile
    const int bc  = gid >> 2;
    const int i0  = (gid & 3) * 64;
    float* p       = attn + (size_t)bc * HWS;
    const float* v = V    + (size_t)bc * HWS;

    __shared__ float As[8][64];            // attn tile, [k][i]
    __shared__ float Bs[8][256];           // v tile,    [k][j]

    const int tid = threadIdx.x;
    const int tx  = tid & 31;              // 32 j-groups (covers all 256 cols)
    const int ty  = tid >> 5;              // 8 i-groups

    float acc[8][8];
#pragma unroll
    for (int u = 0; u < 8; ++u)
#pragma unroll
        for (int w = 0; w < 8; ++w) acc[u][w] = 0.f;

    for (int m0 = 0; m0 < WW; m0 += 8) {
        if (tid < 128) {                   // stage As: 64 rows x 8 k-vals
            const int i    = tid >> 1;
            const int half = (tid & 1) * 4;
            const float4 t4 = *(const float4*)&p[(size_t)(i0 + i) * WW + m0 + half];
            As[half + 0][i] = t4.x; As[half + 1][i] = t4.y;
            As[half + 2][i] = t4.z; As[half + 3][i] = t4.w;
        }
        {                                  // stage Bs: 8 rows x 256 cols
            const int kk = tid >> 5;
            const int j  = (tid & 31) * 8;
            *(float4*)&Bs[kk][j]     = *(const float4*)&v[(size_t)(m0 + kk) * WW + j];
            *(float4*)&Bs[kk][j + 4] = *(const float4*)&v[(size_t)(m0 + kk) * WW + j + 4];
        }
        __syncthreads();
#pragma unroll
        for (int kk = 0; kk < 8; ++kk) {
            float a[8], bvv[8];
#pragma unroll
            for (int u = 0; u < 8; ++u) a[u]   = As[kk][ty * 8 + u];
#pragma unroll
            for (int u = 0; u < 8; ++u) bvv[u] = Bs[kk][tx * 8 + u];
#pragma unroll
            for (int u = 0; u < 8; ++u)
#pragma unroll
                for (int w = 0; w < 8; ++w)
                    acc[u][w] = fmaf(a[u], bvv[w], acc[u][w]);
        }
        __syncthreads();                   // final barrier also fences the in-place epilogue
    }

#pragma unroll
    for (int u = 0; u < 8; ++u) {
        float* row = p + (size_t)(i0 + ty * 8 + u) * WW + tx * 8;
#pragma unroll
        for (int w = 0; w < 8; ++w) row[w] = acc[u][w];
    }
}

// ---------------------------------------------------------------------------
extern "C" void kernel_launch(void* const* d_in, const int* in_sizes, int n_in,
                              void* d_out, int out_size, void* d_ws, size_t ws_size,
                              hipStream_t stream) {
    const float* x  = (const float*)d_in[0];
    const float* Wq = (const float*)d_in[1];
    const float* bq = (const float*)d_in[2];
    const float* Wk = (const float*)d_in[3];
    const float* bk = (const float*)d_in[4];
    const float* Wv = (const float*)d_in[5];
    const float* bv = (const float*)d_in[6];
    float* out = (float*)d_out;

    // Workspace: Q, K, V fp32, 128 MiB each.
    const size_t NELEM = (size_t)NB * CH * HWS;     // 33,554,432
    float* Q  = (float*)d_ws;
    float* Kb = Q + NELEM;
    float* Vb = Kb + NELEM;

    const int qkvBlocks = (NB * HWS) / 128;         // 4096 N-tiles of 128 pixels
    qkv_kernel2<<<qkvBlocks, 256, 0, stream>>>(x, Wq, bq, Wk, bk, Wv, bv, Q, Kb, Vb);

    const int attnBlocks = NB * CH * 4;             // 2048 (2x2 tiles of 128)
    attn_kernel<<<attnBlocks, 256, 0, stream>>>(Q, Kb, out);

    const int smBlocks = NB * WW;                   // 2048
    softmax_kernel<<<smBlocks, 256, 0, stream>>>(out);

    const int pvBlocks = NB * CH * 4;               // 2048 (i-tiles of 64)
    pv_kernel<<<pvBlocks, 256, 0, stream>>>(out, Vb);
}

// Round 4
// 746.494 us; speedup vs baseline: 1.9578x; 1.1997x over previous
//
#include <hip/hip_runtime.h>
#include <math.h>

// Problem constants: B=8, C=64, H=W=256, fp32 in/out.
constexpr int CH  = 64;      // channels
constexpr int WW  = 256;     // H == W
constexpr int HWS = WW * WW; // 65536 elements per (b,c) slab
constexpr int NB  = 8;       // batch

typedef __attribute__((ext_vector_type(8))) short bf16x8;
typedef __attribute__((ext_vector_type(4))) float f32x4;

// RNE fp32 -> bf16 (manual; data is finite)
__device__ inline ushort f2bf(float f) {
    uint u = __float_as_uint(f);
    u += 0x7fffu + ((u >> 16) & 1u);
    return (ushort)(u >> 16);
}

// ---------------------------------------------------------------------------
// Kernel 1: fused QKV projection GEMM.  C[192 x 524288] = W[192x64] * X[64x524288]
// Q,K written fp32 [h][i]; V written bf16 (feeds MFMA PV).
// ---------------------------------------------------------------------------
__global__ __launch_bounds__(256) void qkv_kernel2(
    const float* __restrict__ x,
    const float* __restrict__ Wq, const float* __restrict__ bq,
    const float* __restrict__ Wk, const float* __restrict__ bk,
    const float* __restrict__ Wv, const float* __restrict__ bv,
    float* __restrict__ Q, float* __restrict__ K, ushort* __restrict__ V)
{
    __shared__ float Wt[64][192];   // [c][m], m = mat*64 + o   (48 KB)
    __shared__ float Bias[192];
    __shared__ float Xs[8][128];    // K-chunk x N-tile          (4 KB)

    const int tid = threadIdx.x;
    const int n0  = blockIdx.x * 128;   // global pixel
    const int b   = n0 >> 16;
    const int pb  = n0 & 65535;

    // Stage weights transposed. Lane-major over o => consecutive LDS addrs.
    {
        const float* Wsrc[3] = {Wq, Wk, Wv};
#pragma unroll
        for (int mat = 0; mat < 3; ++mat) {
#pragma unroll
            for (int r = 0; r < 4; ++r) {
                const int flat = r * 256 + tid;   // 0..1023
                const int o    = flat & 63;       // consecutive across lanes
                const int c4   = (flat >> 6) * 4; // 0,4,...,60
                const float4 w = *(const float4*)&Wsrc[mat][o * 64 + c4];
                Wt[c4 + 0][mat * 64 + o] = w.x;
                Wt[c4 + 1][mat * 64 + o] = w.y;
                Wt[c4 + 2][mat * 64 + o] = w.z;
                Wt[c4 + 3][mat * 64 + o] = w.w;
            }
        }
        if (tid < 192)
            Bias[tid] = (tid < 64) ? bq[tid] : ((tid < 128) ? bk[tid - 64] : bv[tid - 128]);
    }

    const int mg  = tid >> 5;        // 0..7
    const int ng  = tid & 31;        // 0..31
    const int m0  = mg * 24;
    const int pix = ng * 4;

    float4 acc[24];
#pragma unroll
    for (int m = 0; m < 24; ++m) acc[m] = make_float4(0.f, 0.f, 0.f, 0.f);

    const int skk = tid >> 5;
    const int sp4 = (tid & 31) * 4;

    for (int c0 = 0; c0 < CH; c0 += 8) {
        __syncthreads();
        *(float4*)&Xs[skk][sp4] =
            *(const float4*)&x[((size_t)(b * CH + c0 + skk) << 16) + pb + sp4];
        __syncthreads();

#pragma unroll
        for (int kk = 0; kk < 8; ++kk) {
            float wv[24];
#pragma unroll
            for (int q4 = 0; q4 < 6; ++q4)
                *(float4*)&wv[q4 * 4] = *(const float4*)&Wt[c0 + kk][m0 + q4 * 4];
            const float4 xv = *(const float4*)&Xs[kk][pix];
#pragma unroll
            for (int m = 0; m < 24; ++m) {
                acc[m].x = fmaf(wv[m], xv.x, acc[m].x);
                acc[m].y = fmaf(wv[m], xv.y, acc[m].y);
                acc[m].z = fmaf(wv[m], xv.z, acc[m].z);
                acc[m].w = fmaf(wv[m], xv.w, acc[m].w);
            }
        }
    }

#pragma unroll
    for (int m = 0; m < 24; ++m) {
        const int gm  = m0 + m;
        const int mat = gm >> 6;
        const int ch  = gm & 63;
        const float bias = Bias[gm];
        float4 r = acc[m];
        r.x += bias; r.y += bias; r.z += bias; r.w += bias;
        const size_t oidx = ((size_t)(b * CH + ch) << 16) + pb + pix;
        if (mat == 0)      *(float4*)&Q[oidx] = r;
        else if (mat == 1) *(float4*)&K[oidx] = r;
        else {
            ushort4 vs;
            vs.x = f2bf(r.x); vs.y = f2bf(r.y); vs.z = f2bf(r.z); vs.w = f2bf(r.w);
            *(ushort4*)&V[oidx] = vs;
        }
    }
}

// ---------------------------------------------------------------------------
// Kernel 2: attn[b,c,i,j] = sum_h q[b,c,h,i] * k[b,c,h,j]  (fp32 this round)
// ---------------------------------------------------------------------------
__global__ __launch_bounds__(256) void attn_kernel(
    const float* __restrict__ Q, const float* __restrict__ Kt,
    float* __restrict__ attn)
{
    const int gid = blockIdx.x;
    const int bc  = gid >> 2;
    const int i0  = ((gid >> 1) & 1) * 128;
    const int j0  = (gid & 1) * 128;
    const float* q = Q  + (size_t)bc * HWS;
    const float* k = Kt + (size_t)bc * HWS;
    float* out     = attn + (size_t)bc * HWS;

    __shared__ float As[8][128];
    __shared__ float Bs[8][128];

    const int tid = threadIdx.x;
    const int tx  = tid & 15;
    const int ty  = tid >> 4;

    float acc[8][8];
#pragma unroll
    for (int u = 0; u < 8; ++u)
#pragma unroll
        for (int w = 0; w < 8; ++w) acc[u][w] = 0.f;

    const int sflat = tid * 4;
    const int skk   = sflat >> 7;
    const int sii   = sflat & 127;

    for (int k0 = 0; k0 < WW; k0 += 8) {
        *(float4*)&As[skk][sii] = *(const float4*)&q[(k0 + skk) * WW + i0 + sii];
        *(float4*)&Bs[skk][sii] = *(const float4*)&k[(k0 + skk) * WW + j0 + sii];
        __syncthreads();
#pragma unroll
        for (int kk = 0; kk < 8; ++kk) {
            float a[8], bvv[8];
#pragma unroll
            for (int u = 0; u < 8; ++u) a[u]   = As[kk][ty * 8 + u];
#pragma unroll
            for (int u = 0; u < 8; ++u) bvv[u] = Bs[kk][tx * 8 + u];
#pragma unroll
            for (int u = 0; u < 8; ++u)
#pragma unroll
                for (int w = 0; w < 8; ++w)
                    acc[u][w] = fmaf(a[u], bvv[w], acc[u][w]);
        }
        __syncthreads();
    }
#pragma unroll
    for (int u = 0; u < 8; ++u) {
        float* row = out + (size_t)(i0 + ty * 8 + u) * WW + j0 + tx * 8;
#pragma unroll
        for (int w = 0; w < 8; ++w) row[w] = acc[u][w];
    }
}

// ---------------------------------------------------------------------------
// Kernel 3: transpose V (bf16): Vt[b,c,j,m] = Vb[b,c,m,j].
// 128x128 LDS tile, row-group rotation swizzle, b128 LDS ops, coalesced
// global loads and stores.
// ---------------------------------------------------------------------------
__global__ __launch_bounds__(256) void transpose_v(
    const ushort* __restrict__ Vb, ushort* __restrict__ Vt)
{
    const int blk = blockIdx.x;
    const int bc  = blk >> 2;
    const int m0  = ((blk >> 1) & 1) * 128;
    const int j0  = (blk & 1) * 128;
    const ushort* src = Vb + (size_t)bc * HWS;
    ushort* dst       = Vt + (size_t)bc * HWS;

    __shared__ ushort T[128][128] __attribute__((aligned(16)));

    const int tid = threadIdx.x;
#pragma unroll
    for (int p = 0; p < 8; ++p) {
        const int id  = p * 256 + tid;
        const int mm  = id >> 4;
        const int c16 = id & 15;               // jj-group
        const int cg  = (c16 + (mm >> 3)) & 15;
        *(uint4*)&T[mm][cg * 8] =
            *(const uint4*)(src + (size_t)(m0 + mm) * WW + j0 + c16 * 8);
    }
    __syncthreads();
#pragma unroll
    for (int p = 0; p < 4; ++p) {
        const int id  = p * 256 + tid;
        const int c16 = id & 15;               // m-chunk (lane-fast => coalesced stores)
        const int jjp = id >> 4;               // 0..63 (row pair)
        const int jj  = jjp * 2;
        const int jjg = jj >> 3;
        ushort ra[8], rb[8];
#pragma unroll
        for (int u = 0; u < 8; ++u) {
            const int mm = c16 * 8 + u;        // mm>>3 == c16
            const int cg = (jjg + c16) & 15;
            const uint pr = *(const uint*)&T[mm][cg * 8 + (jj & 7)];
            ra[u] = (ushort)(pr & 0xffffu);
            rb[u] = (ushort)(pr >> 16);
        }
        *(uint4*)(dst + (size_t)(j0 + jj)     * WW + m0 + c16 * 8) = *(uint4*)ra;
        *(uint4*)(dst + (size_t)(j0 + jj + 1) * WW + m0 + c16 * 8) = *(uint4*)rb;
    }
}

// ---------------------------------------------------------------------------
// Kernel 4: channel softmax, fp32 logits in -> bf16 weights out.
// ---------------------------------------------------------------------------
__global__ __launch_bounds__(128) void softmax_kernel(
    const float* __restrict__ logits, ushort* __restrict__ Wb)
{
    const int gid = blockIdx.x;            // b*256 + i
    const int b   = gid >> 8;
    const int i   = gid & 255;
    const int j2  = threadIdx.x * 2;
    const size_t off = (((size_t)(b * CH)) << 16) + (size_t)i * WW + j2;
    const float* base = logits + off;
    ushort* wout      = Wb + off;

    float2 v[CH];
#pragma unroll
    for (int c = 0; c < CH; ++c) v[c] = *(const float2*)&base[((size_t)c) << 16];

    float mx = v[0].x, my = v[0].y;
#pragma unroll
    for (int c = 1; c < CH; ++c) { mx = fmaxf(mx, v[c].x); my = fmaxf(my, v[c].y); }

    float sx = 0.f, sy = 0.f;
#pragma unroll
    for (int c = 0; c < CH; ++c) {
        v[c].x = __expf(v[c].x - mx); sx += v[c].x;
        v[c].y = __expf(v[c].y - my); sy += v[c].y;
    }
    const float ix = 1.0f / sx, iy = 1.0f / sy;
#pragma unroll
    for (int c = 0; c < CH; ++c) {
        ushort2 o;
        o.x = f2bf(v[c].x * ix);
        o.y = f2bf(v[c].y * iy);
        *(ushort2*)&wout[((size_t)c) << 16] = o;
    }
}

// ---------------------------------------------------------------------------
// Kernel 5: PV via bf16 MFMA.  out[i][j] = sum_m w[i][m] * v[m][j], per (b,c).
// A = w [i][m] (k-contiguous), B = Vt [j][m] (k-contiguous). fp32 accumulate.
// 128x128 block tile, 4 waves each 64x64 (4x4 MFMA 16x16x32 tiles).
// K-stage = 32 -> exactly ONE mfma_16x16x32 per tile pair per stage
// (fragment k-offset quad*8; the R3 ks-loop read past the staged tile -> NaN).
// ---------------------------------------------------------------------------
__global__ __launch_bounds__(256) void pv_kernel2(
    const ushort* __restrict__ Wb, const ushort* __restrict__ Vt,
    float* __restrict__ out)
{
    const int blk = blockIdx.x;
    const int bc  = blk >> 2;
    const int i0  = ((blk >> 1) & 1) * 128;
    const int j0  = (blk & 1) * 128;
    const ushort* w  = Wb + (size_t)bc * HWS;
    const ushort* vt = Vt + (size_t)bc * HWS;
    float* o         = out + (size_t)bc * HWS;

    __shared__ ushort As[128][40] __attribute__((aligned(16)));
    __shared__ ushort Bs[128][40] __attribute__((aligned(16)));

    const int tid  = threadIdx.x;
    const int L    = tid & 63;
    const int wid  = tid >> 6;
    const int wy   = (wid >> 1) * 64;
    const int wx   = (wid & 1) * 64;
    const int ml   = L & 15;
    const int quad = L >> 4;

    f32x4 zero = {0.f, 0.f, 0.f, 0.f};
    f32x4 acc[4][4];
#pragma unroll
    for (int a = 0; a < 4; ++a)
#pragma unroll
        for (int b = 0; b < 4; ++b) acc[a][b] = zero;

    for (int m0 = 0; m0 < WW; m0 += 32) {
#pragma unroll
        for (int p = 0; p < 2; ++p) {
            const int id  = p * 256 + tid;
            const int row = id >> 2;
            const int c4  = id & 3;
            *(uint4*)&As[row][c4 * 8] =
                *(const uint4*)(w  + (size_t)(i0 + row) * WW + m0 + c4 * 8);
            *(uint4*)&Bs[row][c4 * 8] =
                *(const uint4*)(vt + (size_t)(j0 + row) * WW + m0 + c4 * 8);
        }
        __syncthreads();

        bf16x8 af[4], bfr[4];
#pragma unroll
        for (int t = 0; t < 4; ++t)
            af[t]  = *(const bf16x8*)&As[wy + t * 16 + ml][quad * 8];
#pragma unroll
        for (int t = 0; t < 4; ++t)
            bfr[t] = *(const bf16x8*)&Bs[wx + t * 16 + ml][quad * 8];
#pragma unroll
        for (int a = 0; a < 4; ++a)
#pragma unroll
            for (int b = 0; b < 4; ++b)
                acc[a][b] = __builtin_amdgcn_mfma_f32_16x16x32_bf16(
                    af[a], bfr[b], acc[a][b], 0, 0, 0);
        __syncthreads();
    }

    // C/D layout: col = lane&15, row = quad*4 + reg
#pragma unroll
    for (int a = 0; a < 4; ++a)
#pragma unroll
        for (int b = 0; b < 4; ++b)
#pragma unroll
            for (int r = 0; r < 4; ++r)
                o[(size_t)(i0 + wy + a * 16 + quad * 4 + r) * WW
                  + j0 + wx + b * 16 + ml] = acc[a][b][r];
}

// ---------------------------------------------------------------------------
extern "C" void kernel_launch(void* const* d_in, const int* in_sizes, int n_in,
                              void* d_out, int out_size, void* d_ws, size_t ws_size,
                              hipStream_t stream) {
    const float* x  = (const float*)d_in[0];
    const float* Wq = (const float*)d_in[1];
    const float* bq = (const float*)d_in[2];
    const float* Wk = (const float*)d_in[3];
    const float* bk = (const float*)d_in[4];
    const float* Wv = (const float*)d_in[5];
    const float* bv = (const float*)d_in[6];
    float* out = (float*)d_out;

    // ws layout (402.7 MB):
    //   Q fp32 [134MB] | K fp32 [134MB] | Vb bf16 [67MB] | Vt bf16 [67MB]
    //   Wb (softmax bf16) aliases Q — Q is dead after attn_kernel.
    const size_t NEL = (size_t)NB * CH * HWS;       // 33,554,432
    float*  Q  = (float*)d_ws;
    float*  K  = Q + NEL;
    ushort* Vb = (ushort*)(K + NEL);
    ushort* Vt = Vb + NEL;
    ushort* Wb = (ushort*)d_ws;                     // alias Q

    qkv_kernel2<<<(NB * HWS) / 128, 256, 0, stream>>>(x, Wq, bq, Wk, bk, Wv, bv, Q, K, Vb);
    attn_kernel<<<NB * CH * 4, 256, 0, stream>>>(Q, K, out);
    transpose_v<<<NB * CH * 4, 256, 0, stream>>>(Vb, Vt);
    softmax_kernel<<<NB * WW, 128, 0, stream>>>(out, Wb);
    pv_kernel2<<<NB * CH * 4, 256, 0, stream>>>(Wb, Vt, out);
}